// Round 1
// baseline (1044.053 us; speedup 1.0000x reference)
//
#include <hip/hip_runtime.h>
#include <hip/hip_bf16.h>
#include <cstdint>

#define B_ 512
#define T_ 48
#define N_ 62
#define F_ 5
#define E_ 496
#define H_ 512
#define NF_ 310      // N*F
#define SEQP 320     // padded seq row (310 -> 320)
#define KPAD 832     // 320 + 512
#define EPS_ 1e-5f

typedef __attribute__((ext_vector_type(8))) short short8;
typedef __attribute__((ext_vector_type(4))) float f32x4;

__device__ __forceinline__ float sigm(float x)  { return 1.f / (1.f + __expf(-x)); }
__device__ __forceinline__ float tanhf_(float x){ return 2.f / (1.f + __expf(-2.f*x)) - 1.f; }

// ---------------- ChebConv (K=3) + BN partial stats, one block per graph ----------------
__global__ __launch_bounds__(320) void k_cheb(
    const float* __restrict__ x, const int* __restrict__ esrc, const int* __restrict__ edst,
    const float* __restrict__ ew, const float* __restrict__ Wc, const float* __restrict__ bc,
    float* __restrict__ cheb, float* __restrict__ bps, float* __restrict__ bpq)
{
  __shared__ float A[N_*N_];
  __shared__ float dinv[N_];
  __shared__ float X0[NF_], T1s[NF_], T2s[NF_], OUT[NF_];
  __shared__ float wcs[75];
  const int tid = threadIdx.x;
  const int b = blockIdx.x;

  for (int i = tid; i < N_*N_; i += 320) A[i] = 0.f;
  __syncthreads();
  for (int e = tid; e < E_; e += 320) {
    int s = esrc[b*E_ + e], d = edst[b*E_ + e];
    atomicAdd(&A[d*N_ + s], ew[b*E_ + e]);
  }
  __syncthreads();
  if (tid < N_) {
    float s = 0.f;
    for (int m = 0; m < N_; ++m) s += A[tid*N_ + m];
    dinv[tid] = (s > 0.f) ? rsqrtf(s) : 0.f;
  }
  __syncthreads();
  for (int i = tid; i < N_*N_; i += 320) {
    int n = i / N_, m = i % N_;
    A[i] = -dinv[n] * A[i] * dinv[m];   // Lhat in place
  }
  __syncthreads();

  const int n = tid / F_, f = tid % F_;
  float lrow[N_];
  if (tid < NF_) {
    #pragma unroll
    for (int m = 0; m < N_; ++m) lrow[m] = A[n*N_ + m];
  }

  for (int t = 0; t < T_; ++t) {
    if (tid < NF_) X0[tid] = x[((size_t)b*T_ + t)*NF_ + tid];
    if (tid < 75)  wcs[tid] = Wc[t*75 + tid];      // [k][f][g]
    __syncthreads();
    if (tid < NF_) {
      float t1 = 0.f;
      #pragma unroll
      for (int m = 0; m < N_; ++m) t1 = fmaf(lrow[m], X0[m*F_ + f], t1);
      T1s[tid] = t1;
    }
    __syncthreads();
    if (tid < NF_) {
      float t2 = 0.f;
      #pragma unroll
      for (int m = 0; m < N_; ++m) t2 = fmaf(lrow[m], T1s[m*F_ + f], t2);
      T2s[tid] = 2.f*t2 - X0[tid];
    }
    __syncthreads();
    if (tid < NF_) {     // here (n, g=f)
      float v = bc[t*F_ + f];
      #pragma unroll
      for (int ff = 0; ff < F_; ++ff) {
        v = fmaf(X0 [n*F_ + ff], wcs[      ff*F_ + f], v);
        v = fmaf(T1s[n*F_ + ff], wcs[25 +  ff*F_ + f], v);
        v = fmaf(T2s[n*F_ + ff], wcs[50 +  ff*F_ + f], v);
      }
      OUT[tid] = v;
      cheb[((size_t)t*B_ + b)*NF_ + tid] = v;
    }
    __syncthreads();
    if (tid < F_) {
      float s = 0.f, q = 0.f;
      #pragma unroll
      for (int nn = 0; nn < N_; ++nn) { float v = OUT[nn*F_ + tid]; s += v; q += v*v; }
      bps[(t*F_ + tid)*B_ + b] = s;
      bpq[(t*F_ + tid)*B_ + b] = q;
    }
    __syncthreads();
  }
}

// ---------------- finalize BN scale/shift per (t,f) ----------------
__global__ __launch_bounds__(64) void k_bnfin(
    const float* __restrict__ bps, const float* __restrict__ bpq,
    const float* __restrict__ bng, const float* __restrict__ bnb,
    float* __restrict__ alpha, float* __restrict__ bet)
{
  const int tf = blockIdx.x;
  const int lane = threadIdx.x;
  float s = 0.f, q = 0.f;
  for (int i = lane; i < B_; i += 64) { s += bps[tf*B_ + i]; q += bpq[tf*B_ + i]; }
  #pragma unroll
  for (int off = 32; off; off >>= 1) { s += __shfl_down(s, off); q += __shfl_down(q, off); }
  if (lane == 0) {
    const float cnt = (float)(B_*N_);
    float mu = s / cnt;
    float var = q / cnt - mu*mu;
    float al = bng[tf] * rsqrtf(var + EPS_);
    alpha[tf] = al;
    bet[tf] = bnb[tf] - mu*al;
  }
}

// ---------------- BN apply + pack to bf16 padded sequence [t][b][320] ----------------
__global__ __launch_bounds__(256) void k_seq(
    const float* __restrict__ cheb, const float* __restrict__ alpha, const float* __restrict__ bet,
    __hip_bfloat16* __restrict__ seqb)
{
  int idx = blockIdx.x*256 + threadIdx.x;     // T*B*320
  int k = idx % SEQP;
  int tb = idx / SEQP;                        // t*B + b
  float v = 0.f;
  if (k < NF_) {
    int t = tb / B_;
    int tf = t*F_ + (k % F_);
    v = cheb[(size_t)tb*NF_ + k] * alpha[tf] + bet[tf];
  }
  seqb[idx] = __float2bfloat16(v);
}

// ---------------- build bf16 W_cat (2048 x 832): [W_ih | pad | W_hh] ----------------
__global__ __launch_bounds__(256) void k_wcat(
    const float* __restrict__ Wih, const float* __restrict__ Whh,
    __hip_bfloat16* __restrict__ Wcat)
{
  int j = blockIdx.x;                          // 0..2047
  for (int k = threadIdx.x; k < KPAD; k += 256) {
    float v = 0.f;
    if (k < NF_) v = Wih[(size_t)j*NF_ + k];
    else if (k >= SEQP) v = Whh[(size_t)j*H_ + (k - SEQP)];
    Wcat[(size_t)j*KPAD + k] = __float2bfloat16(v);
  }
}

// ---------------- one LSTM step: gates GEMM (MFMA) + fused cell update ----------------
__global__ __launch_bounds__(256) void k_step(
    const __hip_bfloat16* __restrict__ seqt,   // (B, 320)
    const __hip_bfloat16* __restrict__ hin,    // (B, 512)
    const __hip_bfloat16* __restrict__ Wcat,   // (2048, 832)
    const float* __restrict__ bih, const float* __restrict__ bhh,
    float* __restrict__ cbuf, float* __restrict__ y,
    __hip_bfloat16* __restrict__ hout, int t)
{
  const int tid = threadIdx.x;
  const int lane = tid & 63;
  const int wv  = tid >> 6;
  const int l16 = lane & 15;
  const int lhi = lane >> 4;
  const int b0 = blockIdx.x * 64;
  const int j0 = blockIdx.y * 16;

  const short* sseq = (const short*)seqt;
  const short* sh   = (const short*)hin;
  const short* sw   = (const short*)Wcat;

  const int arow = b0 + wv*16 + l16;
  const short* ap0 = sseq + (size_t)arow*SEQP + lhi*8;
  const short* ap1 = sh   + (size_t)arow*H_   + lhi*8;
  const short* bp0 = sw + (size_t)(0*H_ + j0 + l16)*KPAD + lhi*8;
  const short* bp1 = sw + (size_t)(1*H_ + j0 + l16)*KPAD + lhi*8;
  const short* bp2 = sw + (size_t)(2*H_ + j0 + l16)*KPAD + lhi*8;
  const short* bp3 = sw + (size_t)(3*H_ + j0 + l16)*KPAD + lhi*8;

  f32x4 acc0 = {0.f,0.f,0.f,0.f}, acc1 = acc0, acc2 = acc0, acc3 = acc0;
  #pragma unroll
  for (int kk = 0; kk < 10; ++kk) {            // seq part of K
    short8 a  = *(const short8*)(ap0 + kk*32);
    short8 w0 = *(const short8*)(bp0 + kk*32);
    short8 w1 = *(const short8*)(bp1 + kk*32);
    short8 w2 = *(const short8*)(bp2 + kk*32);
    short8 w3 = *(const short8*)(bp3 + kk*32);
    acc0 = __builtin_amdgcn_mfma_f32_16x16x32_bf16(a, w0, acc0, 0, 0, 0);
    acc1 = __builtin_amdgcn_mfma_f32_16x16x32_bf16(a, w1, acc1, 0, 0, 0);
    acc2 = __builtin_amdgcn_mfma_f32_16x16x32_bf16(a, w2, acc2, 0, 0, 0);
    acc3 = __builtin_amdgcn_mfma_f32_16x16x32_bf16(a, w3, acc3, 0, 0, 0);
  }
  #pragma unroll
  for (int kk = 0; kk < 16; ++kk) {            // h part of K
    short8 a  = *(const short8*)(ap1 + kk*32);
    short8 w0 = *(const short8*)(bp0 + (kk+10)*32);
    short8 w1 = *(const short8*)(bp1 + (kk+10)*32);
    short8 w2 = *(const short8*)(bp2 + (kk+10)*32);
    short8 w3 = *(const short8*)(bp3 + (kk+10)*32);
    acc0 = __builtin_amdgcn_mfma_f32_16x16x32_bf16(a, w0, acc0, 0, 0, 0);
    acc1 = __builtin_amdgcn_mfma_f32_16x16x32_bf16(a, w1, acc1, 0, 0, 0);
    acc2 = __builtin_amdgcn_mfma_f32_16x16x32_bf16(a, w2, acc2, 0, 0, 0);
    acc3 = __builtin_amdgcn_mfma_f32_16x16x32_bf16(a, w3, acc3, 0, 0, 0);
  }

  const int j = j0 + l16;
  const float bi = bih[0*H_ + j] + bhh[0*H_ + j];
  const float bf = bih[1*H_ + j] + bhh[1*H_ + j];
  const float bg = bih[2*H_ + j] + bhh[2*H_ + j];
  const float bo = bih[3*H_ + j] + bhh[3*H_ + j];
  const int drow = b0 + wv*16 + lhi*4;         // D layout: row = 4*(lane>>4)+r, col = lane&15
  #pragma unroll
  for (int r = 0; r < 4; ++r) {
    const int bb = drow + r;
    float ig = sigm(acc0[r] + bi);
    float fg = sigm(acc1[r] + bf);
    float gg = tanhf_(acc2[r] + bg);
    float og = sigm(acc3[r] + bo);
    float cn = fg * cbuf[bb*H_ + j] + ig*gg;
    cbuf[bb*H_ + j] = cn;
    float h = og * tanhf_(cn);
    y[((size_t)bb*T_ + t)*H_ + j] = h;
    hout[bb*H_ + j] = __float2bfloat16(h);
  }
}

// ---------------- BN1 partial stats over (B,H) per t ----------------
__global__ __launch_bounds__(256) void k_bn1part(
    const float* __restrict__ y, float* __restrict__ bn1s, float* __restrict__ bn1q)
{
  const int t = blockIdx.x, ch = blockIdx.y, tid = threadIdx.x;
  float s = 0.f, q = 0.f;
  for (int i = tid; i < 64*H_; i += 256) {
    int b = ch*64 + (i >> 9);
    float v = y[((size_t)b*T_ + t)*H_ + (i & 511)];
    s += v; q += v*v;
  }
  __shared__ float rs[256], rq[256];
  rs[tid] = s; rq[tid] = q;
  __syncthreads();
  for (int o = 128; o; o >>= 1) {
    if (tid < o) { rs[tid] += rs[tid+o]; rq[tid] += rq[tid+o]; }
    __syncthreads();
  }
  if (tid == 0) { bn1s[t*8 + ch] = rs[0]; bn1q[t*8 + ch] = rq[0]; }
}

// ---------------- head: fold BN1 + (B, T*H) @ Wl^T + bl, one block per b ----------------
__global__ __launch_bounds__(256) void k_head(
    const float* __restrict__ y, const float* __restrict__ bn1s, const float* __restrict__ bn1q,
    const float* __restrict__ g1, const float* __restrict__ be1,
    const float* __restrict__ Wl, const float* __restrict__ bl, float* __restrict__ out)
{
  const int b = blockIdx.x, tid = threadIdx.x;
  __shared__ float al1[T_], bt1[T_];
  if (tid < T_) {
    float s = 0.f, q = 0.f;
    #pragma unroll
    for (int ch = 0; ch < 8; ++ch) { s += bn1s[tid*8 + ch]; q += bn1q[tid*8 + ch]; }
    const float cnt = (float)(B_*H_);
    float mu = s / cnt, var = q / cnt - mu*mu;
    float al = g1[tid] * rsqrtf(var + EPS_);
    al1[tid] = al; bt1[tid] = be1[tid] - mu*al;
  }
  __syncthreads();
  float a0 = 0.f, a1 = 0.f, a2 = 0.f;
  const float* yb = y + (size_t)b*(T_*H_);
  for (int i = tid; i < T_*H_; i += 256) {
    int t = i >> 9;
    float yn = yb[i]*al1[t] + bt1[t];
    a0 = fmaf(yn, Wl[i],            a0);
    a1 = fmaf(yn, Wl[T_*H_ + i],    a1);
    a2 = fmaf(yn, Wl[2*T_*H_ + i],  a2);
  }
  __shared__ float red[256];
  red[tid] = a0; __syncthreads();
  for (int o = 128; o; o >>= 1) { if (tid < o) red[tid] += red[tid+o]; __syncthreads(); }
  if (!tid) out[b*3 + 0] = red[0] + bl[0];
  __syncthreads();
  red[tid] = a1; __syncthreads();
  for (int o = 128; o; o >>= 1) { if (tid < o) red[tid] += red[tid+o]; __syncthreads(); }
  if (!tid) out[b*3 + 1] = red[0] + bl[1];
  __syncthreads();
  red[tid] = a2; __syncthreads();
  for (int o = 128; o; o >>= 1) { if (tid < o) red[tid] += red[tid+o]; __syncthreads(); }
  if (!tid) out[b*3 + 2] = red[0] + bl[2];
}

extern "C" void kernel_launch(void* const* d_in, const int* in_sizes, int n_in,
                              void* d_out, int out_size, void* d_ws, size_t ws_size,
                              hipStream_t stream)
{
  (void)in_sizes; (void)n_in; (void)out_size;
  const float* x   = (const float*)d_in[0];
  const int* esrc  = (const int*)d_in[1];
  const int* edst  = (const int*)d_in[2];
  const float* ew  = (const float*)d_in[3];
  const float* Wc  = (const float*)d_in[4];
  const float* bc  = (const float*)d_in[5];
  const float* bng = (const float*)d_in[6];
  const float* bnb = (const float*)d_in[7];
  const float* Wih = (const float*)d_in[8];
  const float* Whh = (const float*)d_in[9];
  const float* bih = (const float*)d_in[10];
  const float* bhh = (const float*)d_in[11];
  const float* g1  = (const float*)d_in[12];
  const float* be1 = (const float*)d_in[13];
  const float* Wl  = (const float*)d_in[14];
  const float* bl  = (const float*)d_in[15];
  float* out = (float*)d_out;

  char* ws = (char*)d_ws;
  size_t off = 0;
  auto alloc = [&](size_t bytes) {
    void* p = ws + off;
    off += (bytes + 255) & ~(size_t)255;
    return p;
  };
  float* cheb = (float*)alloc(sizeof(float)*(size_t)T_*B_*NF_);
  float* bps  = (float*)alloc(sizeof(float)*T_*F_*B_);
  float* bpq  = (float*)alloc(sizeof(float)*T_*F_*B_);
  float* alpha= (float*)alloc(sizeof(float)*T_*F_);
  float* bet  = (float*)alloc(sizeof(float)*T_*F_);
  __hip_bfloat16* seqb = (__hip_bfloat16*)alloc(sizeof(__hip_bfloat16)*(size_t)T_*B_*SEQP);
  __hip_bfloat16* Wcat = (__hip_bfloat16*)alloc(sizeof(__hip_bfloat16)*(size_t)4*H_*KPAD);
  __hip_bfloat16* h0   = (__hip_bfloat16*)alloc(sizeof(__hip_bfloat16)*B_*H_);
  __hip_bfloat16* h1   = (__hip_bfloat16*)alloc(sizeof(__hip_bfloat16)*B_*H_);
  float* cbuf = (float*)alloc(sizeof(float)*B_*H_);
  float* y    = (float*)alloc(sizeof(float)*(size_t)B_*T_*H_);
  float* bn1s = (float*)alloc(sizeof(float)*T_*8);
  float* bn1q = (float*)alloc(sizeof(float)*T_*8);
  if (ws_size < off) return;   // workspace too small -> fail loudly (output stays poisoned)

  hipMemsetAsync(h0,   0, sizeof(__hip_bfloat16)*B_*H_, stream);
  hipMemsetAsync(cbuf, 0, sizeof(float)*B_*H_, stream);

  k_cheb<<<B_, 320, 0, stream>>>(x, esrc, edst, ew, Wc, bc, cheb, bps, bpq);
  k_bnfin<<<T_*F_, 64, 0, stream>>>(bps, bpq, bng, bnb, alpha, bet);
  k_seq<<<(T_*B_*SEQP)/256, 256, 0, stream>>>(cheb, alpha, bet, seqb);
  k_wcat<<<4*H_, 256, 0, stream>>>(Wih, Whh, Wcat);

  const __hip_bfloat16* hin = h0;
  __hip_bfloat16* hout = h1;
  for (int t = 0; t < T_; ++t) {
    k_step<<<dim3(B_/64, H_/16), 256, 0, stream>>>(
        seqb + (size_t)t*B_*SEQP, hin, Wcat, bih, bhh, cbuf, y, hout, t);
    __hip_bfloat16* nxt = (hout == h1) ? h0 : h1;
    hin = hout;
    hout = nxt;
  }

  k_bn1part<<<dim3(T_, 8), 256, 0, stream>>>(y, bn1s, bn1q);
  k_head<<<B_, 256, 0, stream>>>(y, bn1s, bn1q, g1, be1, Wl, bl, out);
}